// Round 8
// baseline (880.542 us; speedup 1.0000x reference)
//
#include <hip/hip_runtime.h>
#include <math.h>

// minGRU: hg = x@Whg^T (bf16 MFMA) -> gates+scan (fp32) -> out = h@Wout^T
// 2-slot LDS ring GEMMs sized for multi-block/CU residency (TLP overlap).
// x[4,4096,1024] f32, W_hg[2048,1024], W_out[1024,1024], out[4,4096,1024] f32

typedef unsigned short ushort_t;
typedef __attribute__((ext_vector_type(4))) float f32x4;
typedef __attribute__((ext_vector_type(8))) __bf16 bf16x8;
typedef __attribute__((ext_vector_type(8))) unsigned short u16x8;

constexpr int Bsz  = 4;
constexpr int S    = 4096;
constexpr int Din  = 1024;
constexpr int Dh   = 1024;
constexpr int M    = Bsz * S;      // 16384
constexpr int NCH  = 64;           // scan chunks along S
constexpr int CL   = S / NCH;      // 64

__device__ __forceinline__ unsigned short f2bf(float f) {
    unsigned int u = __float_as_uint(f);
    unsigned int r = (u + 0x7fffu + ((u >> 16) & 1u)) >> 16;   // RTN-even
    return (unsigned short)r;
}
__device__ __forceinline__ float bf2f(unsigned short u) {
    return __uint_as_float(((unsigned int)u) << 16);
}
__device__ __forceinline__ float sigf(float x) {
    x = fminf(fmaxf(x, -30.f), 30.f);
    return 1.0f / (1.0f + __expf(-x));
}
__device__ __forceinline__ void gld_lds16(const ushort_t* g, ushort_t* l) {
    __builtin_amdgcn_global_load_lds(
        (const __attribute__((address_space(1))) void*)g,
        (__attribute__((address_space(3))) void*)l, 16, 0, 0);
}

// one kernel converting all three f32 inputs to bf16
__global__ __launch_bounds__(256) void cvt_all(
    const float* __restrict__ x, const float* __restrict__ whg,
    const float* __restrict__ wout,
    ushort_t* __restrict__ xb, ushort_t* __restrict__ whgb,
    ushort_t* __restrict__ woutb)
{
    constexpr int NX = M * Din / 8;          // 2097152
    constexpr int NW = 2048 * 1024 / 8;      // 262144
    const int i = blockIdx.x * 256 + threadIdx.x;
    const float* src; ushort_t* dst; int k;
    if (i < NX)            { src = x;    dst = xb;    k = i; }
    else if (i < NX + NW)  { src = whg;  dst = whgb;  k = i - NX; }
    else                   { src = wout; dst = woutb; k = i - NX - NW; }
    const float4 a = ((const float4*)src)[(size_t)k * 2];
    const float4 b = ((const float4*)src)[(size_t)k * 2 + 1];
    u16x8 o;
    o[0] = f2bf(a.x); o[1] = f2bf(a.y); o[2] = f2bf(a.z); o[3] = f2bf(a.w);
    o[4] = f2bf(b.x); o[5] = f2bf(b.y); o[6] = f2bf(b.z); o[7] = f2bf(b.w);
    ((u16x8*)dst)[k] = o;
}

// C[M x N] = A[M x K] * B[N x K]^T, bf16 in, f32 accum.
// Tile MT x 256, 8 waves (2Mx4N), phases of K=32, 2-slot LDS ring:
//   MT=256: slot = A 16KB + B 16KB -> 64 KiB total -> 2 blocks/CU
//   MT=128: slot = A  8KB + B 16KB -> 48 KiB total -> 3 blocks/CU
// Round-3 fragment/staging math (st_16x32 swizzle, pre-swizzled global
// source, measured 0 bank conflicts). Phase p (one barrier):
//   reads(p) [slot p&1]; stage(p+1) [slot (p+1)&1]; MFMA; vmcnt(0); barrier.
// RAW: reads(p) after barrier(p-1) which followed all waves' vmcnt(0)
//   draining stage(p). WAR: stage(p+1) overwrites regions whose readers
//   (phase p-1) completed before barrier(p-1), and its LDS writes occur
//   after issue in phase p -> after that barrier. Tail: no stage/no
//   barrier at p = P-1; epilogue doesn't touch LDS.
template<int MT, bool OUT_BF16>
__global__ __launch_bounds__(512, 4) void gemm256(
    const ushort_t* __restrict__ A, int lda,
    const ushort_t* __restrict__ B, int ldb,
    void* __restrict__ Cout, int ldc, int K, int nbx_log2)
{
    constexpr int IM   = MT / 32;        // acc row-frags per wave (8 or 4)
    constexpr int AEL  = MT * 32;        // A slot elements
    __shared__ ushort_t lds[2][AEL + 8192];

    const int P = K >> 5;                // phases (K=1024 -> 32)

    // XCD-bijective block swizzle (gridDim.x % 8 == 0)
    const int nwg = gridDim.x;
    const int cpx = nwg >> 3;
    const int bid = blockIdx.x;
    const int swz = (bid & 7) * cpx + (bid >> 3);
    const int bx  = swz & ((1 << nbx_log2) - 1);
    const int by  = swz >> nbx_log2;
    const int bm0 = by * MT;
    const int bn0 = bx * 256;

    const int t  = threadIdx.x;
    const int w  = t >> 6;           // wave 0..7
    const int l  = t & 63;
    const int wr = w >> 2;           // 0..1 -> MT/2 rows
    const int wc = w & 3;            // 0..3 -> 64 cols

    // fragment read offsets (elements), swizzle folded in
    const int fr = l & 15;
    const int kg = l >> 4;
    const int qp = kg ^ (((fr >> 3) & 1) << 1);
    const int a_base = wr * (MT / 2) * 32 + fr * 32 + qp * 8;   // + i*512
    const int b_base = wc * 2048 + fr * 32 + qp * 8;            // + j*512

    // staging: lane -> (subtile row, quarter); pre-swizzled global source
    const int rs = l >> 2;
    const int lq = (l & 3) ^ (((rs >> 3) & 1) << 1);
    const ushort_t* gA0 = A + (size_t)(bm0 + w * 16 + rs) * lda + lq * 8;
    const ushort_t* gA1 = gA0 + (size_t)128 * lda;   // MT=256 only
    const ushort_t* gB0 = B + (size_t)(bn0 + w * 16 + rs) * ldb + lq * 8;
    const ushort_t* gB1 = gB0 + (size_t)128 * ldb;

    f32x4 acc[IM][4];
    #pragma unroll
    for (int i = 0; i < IM; ++i)
        #pragma unroll
        for (int j = 0; j < 4; ++j)
            acc[i][j] = (f32x4){0.f, 0.f, 0.f, 0.f};

    auto stage = [&](int p) {
        ushort_t* base = &lds[p & 1][0];
        const int ko = p * 32;
        gld_lds16(gA0 + ko, base + w * 512);
        if constexpr (MT == 256)
            gld_lds16(gA1 + ko, base + w * 512 + 4096);
        gld_lds16(gB0 + ko, base + AEL + w * 512);
        gld_lds16(gB1 + ko, base + AEL + w * 512 + 4096);
    };

    // prologue: slot 0
    stage(0);
    asm volatile("s_waitcnt vmcnt(0)" ::: "memory");
    __builtin_amdgcn_s_barrier();

    #pragma unroll 1
    for (int p = 0; p < P; ++p) {
        const ushort_t* la = &lds[p & 1][0];
        const ushort_t* lb = la + AEL;
        __builtin_amdgcn_sched_barrier(0);
        bf16x8 af[IM], bfr[4];
        #pragma unroll
        for (int i = 0; i < IM; ++i)
            af[i] = *reinterpret_cast<const bf16x8*>(&la[a_base + i * 512]);
        #pragma unroll
        for (int j = 0; j < 4; ++j)
            bfr[j] = *reinterpret_cast<const bf16x8*>(&lb[b_base + j * 512]);
        if (p + 1 < P) stage(p + 1);
        __builtin_amdgcn_sched_barrier(0);
        __builtin_amdgcn_s_setprio(1);
        #pragma unroll
        for (int i = 0; i < IM; ++i)
            #pragma unroll
            for (int j = 0; j < 4; ++j)
                acc[i][j] = __builtin_amdgcn_mfma_f32_16x16x32_bf16(
                    af[i], bfr[j], acc[i][j], 0, 0, 0);
        __builtin_amdgcn_s_setprio(0);
        __builtin_amdgcn_sched_barrier(0);
        if (p + 1 < P) {
            asm volatile("s_waitcnt vmcnt(0)" ::: "memory");
            __builtin_amdgcn_s_barrier();
        }
    }

    // epilogue: round-3 scatter stores (measured clean WRITE_SIZE).
    // C/D layout: col = lane&15, row = (lane>>4)*4 + reg
    #pragma unroll
    for (int i = 0; i < IM; ++i) {
        #pragma unroll
        for (int j = 0; j < 4; ++j) {
            const int col = bn0 + wc * 64 + j * 16 + fr;
            #pragma unroll
            for (int r = 0; r < 4; ++r) {
                const int row = bm0 + wr * (MT / 2) + i * 16 + kg * 4 + r;
                if (OUT_BF16)
                    ((ushort_t*)Cout)[(size_t)row * ldc + col] = f2bf(acc[i][j][r]);
                else
                    ((float*)Cout)[(size_t)row * ldc + col] = acc[i][j][r];
            }
        }
    }
}

// ---- scan over S in 3 stages; gates recomputed from bf16 hg on the fly ----

__global__ __launch_bounds__(256) void scan_stage1(
    const ushort_t* __restrict__ hg, float* __restrict__ Abuf,
    float* __restrict__ hlbuf)
{
    const int g     = blockIdx.x * 256 + threadIdx.x;
    const int d     = g & (Dh - 1);
    const int chunk = (g >> 10) & (NCH - 1);
    const int b     = g >> 16;
    const size_t rowbase = (size_t)(b * S + chunk * CL) * 2048;
    float h = 0.0f, Aacc = 1.0f;
    #pragma unroll 4
    for (int i = 0; i < CL; ++i) {
        const float hid  = bf2f(hg[rowbase + (size_t)i * 2048 + d]);
        const float gate = bf2f(hg[rowbase + (size_t)i * 2048 + 1024 + d]);
        const float z  = sigf(gate);
        const float c  = sigf(-gate);
        const float gv = (hid >= 0.0f) ? (hid + 0.5f) : sigf(hid);
        h = fmaf(c, h, z * gv);
        Aacc *= c;
    }
    const size_t o = (size_t)(b * NCH + chunk) * Dh + d;
    Abuf[o]  = Aacc;
    hlbuf[o] = h;
}

__global__ __launch_bounds__(256) void scan_stage2(
    const float* __restrict__ Abuf, const float* __restrict__ hlbuf,
    float* __restrict__ Hs)
{
    const int g = blockIdx.x * 256 + threadIdx.x;   // 0..B*Dh-1
    const int d = g & (Dh - 1);
    const int b = g >> 10;
    float h = 0.0f;
    for (int ch = 0; ch < NCH; ++ch) {
        const size_t o = (size_t)(b * NCH + ch) * Dh + d;
        Hs[o] = h;
        h = fmaf(Abuf[o], h, hlbuf[o]);
    }
}

// replay chunk from Hs; write h (bf16) COMPACT into hout [M][1024]
__global__ __launch_bounds__(256) void scan_stage3(
    const ushort_t* __restrict__ hg, const float* __restrict__ Hs,
    ushort_t* __restrict__ hout)
{
    const int g     = blockIdx.x * 256 + threadIdx.x;
    const int d     = g & (Dh - 1);
    const int chunk = (g >> 10) & (NCH - 1);
    const int b     = g >> 16;
    const size_t rowbase = (size_t)(b * S + chunk * CL) * 2048;
    const size_t hbase   = (size_t)(b * S + chunk * CL) * 1024 + d;
    float h = Hs[(size_t)(b * NCH + chunk) * Dh + d];
    #pragma unroll 4
    for (int i = 0; i < CL; ++i) {
        const size_t ro = rowbase + (size_t)i * 2048;
        const float hid  = bf2f(hg[ro + d]);
        const float gate = bf2f(hg[ro + 1024 + d]);
        const float z  = sigf(gate);
        const float c  = sigf(-gate);
        const float gv = (hid >= 0.0f) ? (hid + 0.5f) : sigf(hid);
        h = fmaf(c, h, z * gv);
        hout[hbase + (size_t)i * 1024] = f2bf(h);
    }
}

extern "C" void kernel_launch(void* const* d_in, const int* in_sizes, int n_in,
                              void* d_out, int out_size, void* d_ws, size_t ws_size,
                              hipStream_t stream)
{
    (void)in_sizes; (void)n_in; (void)out_size; (void)ws_size;
    const float* x    = (const float*)d_in[0];
    const float* Whg  = (const float*)d_in[1];
    const float* Wout = (const float*)d_in[2];
    float* out = (float*)d_out;

    ushort_t* hgbuf = (ushort_t*)d_ws;                  // [M][2048] bf16  67.1 MB
    ushort_t* xb    = hgbuf + (size_t)M * 2048;         // [M][1024] bf16  33.5 MB (x, then h)
    ushort_t* whgb  = xb + (size_t)M * 1024;            // [2048][1024]     4.2 MB
    ushort_t* woutb = whgb + (size_t)2048 * 1024;       // [1024][1024]     2.1 MB
    float*    Abuf  = (float*)(woutb + (size_t)1024 * 1024);
    float*    hlbuf = Abuf + (size_t)Bsz * NCH * Dh;    // 1 MB each
    float*    Hsbuf = hlbuf + (size_t)Bsz * NCH * Dh;

    const dim3 blk(256);

    // fused conversion: (2097152 + 262144 + 131072)/256 = 9728 blocks
    cvt_all<<<dim3(9728), blk, 0, stream>>>(x, Whg, Wout, xb, whgb, woutb);

    // GEMM1: hg[M][2048] = x @ Whg^T (bf16 out); 256x256 tile, grid 8x64=512
    gemm256<256, true><<<dim3(512), dim3(512), 0, stream>>>(
        xb, Din, whgb, Din, hgbuf, 2048, Din, 3);

    scan_stage1<<<dim3(Bsz * NCH * Dh / 256), blk, 0, stream>>>(hgbuf, Abuf, hlbuf);
    scan_stage2<<<dim3(Bsz * Dh / 256), blk, 0, stream>>>(Abuf, hlbuf, Hsbuf);
    scan_stage3<<<dim3(Bsz * NCH * Dh / 256), blk, 0, stream>>>(hgbuf, Hsbuf, xb);

    // GEMM2: out[M][1024] = h @ Wout^T (f32 out); 128x256 tile, grid 4x128=512
    gemm256<128, false><<<dim3(512), dim3(512), 0, stream>>>(
        xb, Dh, woutb, Din, out, 1024, Dh, 2);
}

// Round 9
// 214.594 us; speedup vs baseline: 4.1033x; 4.1033x over previous
//
#include <hip/hip_runtime.h>
#include <math.h>

// minGRU: hg = x@Whg^T (bf16 MFMA, r3 256^2 4-slot schedule) -> gates+scan (fp32)
//         -> out = h@Wout^T (bf16 MFMA, 128x256 2-slot, 2 blocks/CU)
// x[4,4096,1024] f32, W_hg[2048,1024], W_out[1024,1024], out[4,4096,1024] f32

typedef unsigned short ushort_t;
typedef __attribute__((ext_vector_type(4))) float f32x4;
typedef __attribute__((ext_vector_type(8))) __bf16 bf16x8;
typedef __attribute__((ext_vector_type(8))) unsigned short u16x8;

constexpr int Bsz  = 4;
constexpr int S    = 4096;
constexpr int Din  = 1024;
constexpr int Dh   = 1024;
constexpr int M    = Bsz * S;      // 16384
constexpr int NCH  = 64;           // scan chunks along S
constexpr int CL   = S / NCH;      // 64

__device__ __forceinline__ unsigned short f2bf(float f) {
    unsigned int u = __float_as_uint(f);
    unsigned int r = (u + 0x7fffu + ((u >> 16) & 1u)) >> 16;   // RTN-even
    return (unsigned short)r;
}
__device__ __forceinline__ float bf2f(unsigned short u) {
    return __uint_as_float(((unsigned int)u) << 16);
}
__device__ __forceinline__ float sigf(float x) {
    x = fminf(fmaxf(x, -30.f), 30.f);
    return 1.0f / (1.0f + __expf(-x));
}
__device__ __forceinline__ void gld_lds16(const ushort_t* g, ushort_t* l) {
    __builtin_amdgcn_global_load_lds(
        (const __attribute__((address_space(1))) void*)g,
        (__attribute__((address_space(3))) void*)l, 16, 0, 0);
}

// one kernel converting all three f32 inputs to bf16
__global__ __launch_bounds__(256) void cvt_all(
    const float* __restrict__ x, const float* __restrict__ whg,
    const float* __restrict__ wout,
    ushort_t* __restrict__ xb, ushort_t* __restrict__ whgb,
    ushort_t* __restrict__ woutb)
{
    constexpr int NX = M * Din / 8;          // 2097152
    constexpr int NW = 2048 * 1024 / 8;      // 262144
    const int i = blockIdx.x * 256 + threadIdx.x;
    const float* src; ushort_t* dst; int k;
    if (i < NX)            { src = x;    dst = xb;    k = i; }
    else if (i < NX + NW)  { src = whg;  dst = whgb;  k = i - NX; }
    else                   { src = wout; dst = woutb; k = i - NX - NW; }
    const float4 a = ((const float4*)src)[(size_t)k * 2];
    const float4 b = ((const float4*)src)[(size_t)k * 2 + 1];
    u16x8 o;
    o[0] = f2bf(a.x); o[1] = f2bf(a.y); o[2] = f2bf(a.z); o[3] = f2bf(a.w);
    o[4] = f2bf(b.x); o[5] = f2bf(b.y); o[6] = f2bf(b.z); o[7] = f2bf(b.w);
    ((u16x8*)dst)[k] = o;
}

// ============ GEMM1: r3-exact 256x256, 4-slot ring, 1 barrier/phase ========
// C[M x N] = A[M x K] * B[N x K]^T, bf16 in, f32 accum, bf16 out.
__global__ __launch_bounds__(512, 2) void gemm256(
    const ushort_t* __restrict__ A, int lda,
    const ushort_t* __restrict__ B, int ldb,
    ushort_t* __restrict__ Cout, int ldc, int K, int nbx_log2)
{
    __shared__ ushort_t lds[4][2][8192];   // [slot][A=0/B=1][256*32] = 128 KiB

    const int P = K >> 5;                  // phases (K=1024 -> 32)

    // XCD-bijective block swizzle (gridDim.x % 8 == 0)
    const int nwg = gridDim.x;
    const int cpx = nwg >> 3;
    const int bid = blockIdx.x;
    const int swz = (bid & 7) * cpx + (bid >> 3);
    const int bx  = swz & ((1 << nbx_log2) - 1);
    const int by  = swz >> nbx_log2;
    const int bm0 = by * 256;
    const int bn0 = bx * 256;

    const int t  = threadIdx.x;
    const int w  = t >> 6;           // wave 0..7
    const int l  = t & 63;
    const int wr = w >> 1;           // NOTE r3 used w>>1? -- no: r3 used wr=w>>2
    const int wr3 = w >> 2;          // 0..1 -> 128 rows
    const int wc = w & 3;            // 0..3 -> 64 cols
    (void)wr;

    // fragment read offsets (elements), swizzle folded in
    const int fr = l & 15;
    const int kg = l >> 4;
    const int qp = kg ^ (((fr >> 3) & 1) << 1);
    const int a_base = wr3 * 4096 + fr * 32 + qp * 8;  // + i*512
    const int b_base = wc * 2048 + fr * 32 + qp * 8;   // + j*512

    // staging: lane -> (subtile row, quarter); pre-swizzled global source
    const int rs = l >> 2;
    const int lq = (l & 3) ^ (((rs >> 3) & 1) << 1);
    const ushort_t* gA0 = A + (size_t)(bm0 + w * 16 + rs) * lda + lq * 8;
    const ushort_t* gA1 = gA0 + (size_t)128 * lda;
    const ushort_t* gB0 = B + (size_t)(bn0 + w * 16 + rs) * ldb + lq * 8;
    const ushort_t* gB1 = gB0 + (size_t)128 * ldb;

    f32x4 acc[8][4];
    #pragma unroll
    for (int i = 0; i < 8; ++i)
        #pragma unroll
        for (int j = 0; j < 4; ++j)
            acc[i][j] = (f32x4){0.f, 0.f, 0.f, 0.f};

    auto stage = [&](int p) {   // 4 global_load_lds for phase p's slot
        const int s2 = p & 3;
        const int ko = p * 32;
        gld_lds16(gA0 + ko, &lds[s2][0][w * 512]);
        gld_lds16(gA1 + ko, &lds[s2][0][w * 512 + 4096]);
        gld_lds16(gB0 + ko, &lds[s2][1][w * 512]);
        gld_lds16(gB1 + ko, &lds[s2][1][w * 512 + 4096]);
    };

    auto phase_body = [&](int p, bool do_stage) {
        __builtin_amdgcn_s_barrier();
        __builtin_amdgcn_sched_barrier(0);
        const int s = p & 3;
        const ushort_t* la = &lds[s][0][0];
        const ushort_t* lb = &lds[s][1][0];
        bf16x8 af[8], bfr[4];
        #pragma unroll
        for (int i = 0; i < 8; ++i)
            af[i] = *reinterpret_cast<const bf16x8*>(&la[a_base + i * 512]);
        #pragma unroll
        for (int j = 0; j < 4; ++j)
            bfr[j] = *reinterpret_cast<const bf16x8*>(&lb[b_base + j * 512]);
        if (do_stage) stage(p + 2);
        __builtin_amdgcn_sched_barrier(0);
        __builtin_amdgcn_s_setprio(1);
        #pragma unroll
        for (int i = 0; i < 8; ++i)
            #pragma unroll
            for (int j = 0; j < 4; ++j)
                acc[i][j] = __builtin_amdgcn_mfma_f32_16x16x32_bf16(
                    af[i], bfr[j], acc[i][j], 0, 0, 0);
        __builtin_amdgcn_s_setprio(0);
        __builtin_amdgcn_sched_barrier(0);
    };

    // prologue: stage phases 0 and 1 (8 loads in flight)
    stage(0);
    stage(1);

    for (int p = 0; p < P - 1; ++p) {
        asm volatile("s_waitcnt vmcnt(4)" ::: "memory");
        phase_body(p, p < P - 2);
    }
    asm volatile("s_waitcnt vmcnt(0)" ::: "memory");
    phase_body(P - 1, false);

    // C/D layout: col = lane&15, row = (lane>>4)*4 + reg
    #pragma unroll
    for (int i = 0; i < 8; ++i) {
        #pragma unroll
        for (int j = 0; j < 4; ++j) {
            const int col = bn0 + wc * 64 + j * 16 + fr;
            #pragma unroll
            for (int r = 0; r < 4; ++r) {
                const int row = bm0 + wr3 * 128 + i * 16 + kg * 4 + r;
                Cout[(size_t)row * ldc + col] = f2bf(acc[i][j][r]);
            }
        }
    }
}

// ============ GEMM2: 128x256 tile, 2-slot ring, 2 blocks/CU ================
// C[M x N] = A[M x K] * B[N x K]^T, bf16 in, f32 accum, f32 out.
// LDS: 2 x (A 8KB + B 16KB) = 48 KiB; regs: acc 64 + ~55 -> fits 128 cap
// from __launch_bounds__(512,4) -> 4 waves/SIMD -> 2 blocks/CU.
// Sync (r8-verified): phase p = {reads(p) slot p&1; stage(p+1) slot (p+1)&1;
// MFMA; vmcnt(0); barrier}. RAW: reads(p) after barrier(p-1) which followed
// all waves' vmcnt(0) draining stage(p). WAR: stage(p+1) targets slot whose
// readers (phase p-1) completed before barrier(p-1). Tail: no stage/barrier
// at p = P-1.
__global__ __launch_bounds__(512, 4) void gemm128(
    const ushort_t* __restrict__ A, int lda,
    const ushort_t* __restrict__ B, int ldb,
    float* __restrict__ Cout, int ldc, int K, int nbx_log2)
{
    constexpr int AEL = 128 * 32;          // 4096 elements = 8 KiB
    __shared__ ushort_t lds[2][AEL + 8192];

    const int P = K >> 5;

    const int nwg = gridDim.x;
    const int cpx = nwg >> 3;
    const int bid = blockIdx.x;
    const int swz = (bid & 7) * cpx + (bid >> 3);
    const int bx  = swz & ((1 << nbx_log2) - 1);
    const int by  = swz >> nbx_log2;
    const int bm0 = by * 128;
    const int bn0 = bx * 256;

    const int t  = threadIdx.x;
    const int w  = t >> 6;
    const int l  = t & 63;
    const int wr = w >> 2;           // 0..1 -> 64 rows
    const int wc = w & 3;            // 0..3 -> 64 cols

    const int fr = l & 15;
    const int kg = l >> 4;
    const int qp = kg ^ (((fr >> 3) & 1) << 1);
    const int a_base = wr * 2048 + fr * 32 + qp * 8;   // + i*512 (i<4)
    const int b_base = wc * 2048 + fr * 32 + qp * 8;   // + j*512

    const int rs = l >> 2;
    const int lq = (l & 3) ^ (((rs >> 3) & 1) << 1);
    const ushort_t* gA0 = A + (size_t)(bm0 + w * 16 + rs) * lda + lq * 8;
    const ushort_t* gB0 = B + (size_t)(bn0 + w * 16 + rs) * ldb + lq * 8;
    const ushort_t* gB1 = gB0 + (size_t)128 * ldb;

    f32x4 acc[4][4];
    #pragma unroll
    for (int i = 0; i < 4; ++i)
        #pragma unroll
        for (int j = 0; j < 4; ++j)
            acc[i][j] = (f32x4){0.f, 0.f, 0.f, 0.f};

    auto stage = [&](int p) {   // 3 global_load_lds per wave
        ushort_t* base = &lds[p & 1][0];
        const int ko = p * 32;
        gld_lds16(gA0 + ko, base + w * 512);
        gld_lds16(gB0 + ko, base + AEL + w * 512);
        gld_lds16(gB1 + ko, base + AEL + w * 512 + 4096);
    };

    stage(0);
    asm volatile("s_waitcnt vmcnt(0)" ::: "memory");
    __builtin_amdgcn_s_barrier();

    #pragma unroll 1
    for (int p = 0; p < P; ++p) {
        const ushort_t* la = &lds[p & 1][0];
        const ushort_t* lb = la + AEL;
        __builtin_amdgcn_sched_barrier(0);
        bf16x8 af[4], bfr[4];
        #pragma unroll
        for (int i = 0; i < 4; ++i)
            af[i] = *reinterpret_cast<const bf16x8*>(&la[a_base + i * 512]);
        #pragma unroll
        for (int j = 0; j < 4; ++j)
            bfr[j] = *reinterpret_cast<const bf16x8*>(&lb[b_base + j * 512]);
        if (p + 1 < P) stage(p + 1);
        __builtin_amdgcn_sched_barrier(0);
        __builtin_amdgcn_s_setprio(1);
        #pragma unroll
        for (int i = 0; i < 4; ++i)
            #pragma unroll
            for (int j = 0; j < 4; ++j)
                acc[i][j] = __builtin_amdgcn_mfma_f32_16x16x32_bf16(
                    af[i], bfr[j], acc[i][j], 0, 0, 0);
        __builtin_amdgcn_s_setprio(0);
        __builtin_amdgcn_sched_barrier(0);
        if (p + 1 < P) {
            asm volatile("s_waitcnt vmcnt(0)" ::: "memory");
            __builtin_amdgcn_s_barrier();
        }
    }

    #pragma unroll
    for (int i = 0; i < 4; ++i) {
        #pragma unroll
        for (int j = 0; j < 4; ++j) {
            const int col = bn0 + wc * 64 + j * 16 + fr;
            #pragma unroll
            for (int r = 0; r < 4; ++r) {
                const int row = bm0 + wr * 64 + i * 16 + kg * 4 + r;
                Cout[(size_t)row * ldc + col] = acc[i][j][r];
            }
        }
    }
}

// ---- scan over S in 3 stages; gates recomputed from bf16 hg on the fly ----

__global__ __launch_bounds__(256) void scan_stage1(
    const ushort_t* __restrict__ hg, float* __restrict__ Abuf,
    float* __restrict__ hlbuf)
{
    const int g     = blockIdx.x * 256 + threadIdx.x;
    const int d     = g & (Dh - 1);
    const int chunk = (g >> 10) & (NCH - 1);
    const int b     = g >> 16;
    const size_t rowbase = (size_t)(b * S + chunk * CL) * 2048;
    float h = 0.0f, Aacc = 1.0f;
    #pragma unroll 4
    for (int i = 0; i < CL; ++i) {
        const float hid  = bf2f(hg[rowbase + (size_t)i * 2048 + d]);
        const float gate = bf2f(hg[rowbase + (size_t)i * 2048 + 1024 + d]);
        const float z  = sigf(gate);
        const float c  = sigf(-gate);
        const float gv = (hid >= 0.0f) ? (hid + 0.5f) : sigf(hid);
        h = fmaf(c, h, z * gv);
        Aacc *= c;
    }
    const size_t o = (size_t)(b * NCH + chunk) * Dh + d;
    Abuf[o]  = Aacc;
    hlbuf[o] = h;
}

__global__ __launch_bounds__(256) void scan_stage2(
    const float* __restrict__ Abuf, const float* __restrict__ hlbuf,
    float* __restrict__ Hs)
{
    const int g = blockIdx.x * 256 + threadIdx.x;   // 0..B*Dh-1
    const int d = g & (Dh - 1);
    const int b = g >> 10;
    float h = 0.0f;
    for (int ch = 0; ch < NCH; ++ch) {
        const size_t o = (size_t)(b * NCH + ch) * Dh + d;
        Hs[o] = h;
        h = fmaf(Abuf[o], h, hlbuf[o]);
    }
}

// replay chunk from Hs; write h (bf16) COMPACT into hout [M][1024]
__global__ __launch_bounds__(256) void scan_stage3(
    const ushort_t* __restrict__ hg, const float* __restrict__ Hs,
    ushort_t* __restrict__ hout)
{
    const int g     = blockIdx.x * 256 + threadIdx.x;
    const int d     = g & (Dh - 1);
    const int chunk = (g >> 10) & (NCH - 1);
    const int b     = g >> 16;
    const size_t rowbase = (size_t)(b * S + chunk * CL) * 2048;
    const size_t hbase   = (size_t)(b * S + chunk * CL) * 1024 + d;
    float h = Hs[(size_t)(b * NCH + chunk) * Dh + d];
    #pragma unroll 4
    for (int i = 0; i < CL; ++i) {
        const size_t ro = rowbase + (size_t)i * 2048;
        const float hid  = bf2f(hg[ro + d]);
        const float gate = bf2f(hg[ro + 1024 + d]);
        const float z  = sigf(gate);
        const float c  = sigf(-gate);
        const float gv = (hid >= 0.0f) ? (hid + 0.5f) : sigf(hid);
        h = fmaf(c, h, z * gv);
        hout[hbase + (size_t)i * 1024] = f2bf(h);
    }
}

extern "C" void kernel_launch(void* const* d_in, const int* in_sizes, int n_in,
                              void* d_out, int out_size, void* d_ws, size_t ws_size,
                              hipStream_t stream)
{
    (void)in_sizes; (void)n_in; (void)out_size; (void)ws_size;
    const float* x    = (const float*)d_in[0];
    const float* Whg  = (const float*)d_in[1];
    const float* Wout = (const float*)d_in[2];
    float* out = (float*)d_out;

    ushort_t* hgbuf = (ushort_t*)d_ws;                  // [M][2048] bf16  67.1 MB
    ushort_t* xb    = hgbuf + (size_t)M * 2048;         // [M][1024] bf16  33.5 MB (x, then h)
    ushort_t* whgb  = xb + (size_t)M * 1024;            // [2048][1024]     4.2 MB
    ushort_t* woutb = whgb + (size_t)2048 * 1024;       // [1024][1024]     2.1 MB
    float*    Abuf  = (float*)(woutb + (size_t)1024 * 1024);
    float*    hlbuf = Abuf + (size_t)Bsz * NCH * Dh;    // 1 MB each
    float*    Hsbuf = hlbuf + (size_t)Bsz * NCH * Dh;

    const dim3 blk(256);

    // fused conversion: (2097152 + 262144 + 131072)/256 = 9728 blocks
    cvt_all<<<dim3(9728), blk, 0, stream>>>(x, Whg, Wout, xb, whgb, woutb);

    // GEMM1: hg[M][2048] = x @ Whg^T (bf16 out); 256x256 tile, grid 8x64=512
    gemm256<<<dim3(512), dim3(512), 0, stream>>>(
        xb, Din, whgb, Din, hgbuf, 2048, Din, 3);

    scan_stage1<<<dim3(Bsz * NCH * Dh / 256), blk, 0, stream>>>(hgbuf, Abuf, hlbuf);
    scan_stage2<<<dim3(Bsz * Dh / 256), blk, 0, stream>>>(Abuf, hlbuf, Hsbuf);
    scan_stage3<<<dim3(Bsz * NCH * Dh / 256), blk, 0, stream>>>(hgbuf, Hsbuf, xb);

    // GEMM2: out[M][1024] = h @ Wout^T (f32 out); 128x256 tile, grid 4x128=512
    gemm128<<<dim3(512), dim3(512), 0, stream>>>(
        xb, Dh, woutb, Din, out, 1024, Dh, 2);
}